// Round 1
// baseline (321.586 us; speedup 1.0000x reference)
//
#include <hip/hip_runtime.h>
#include <stdint.h>

// Causal attention, B=4, SQ=SK=2048, D=1024, fp32 in/out, bf16 MFMA compute.
// Structure: QBLK=16 q-rows per block, 8 waves each owning a 128-wide D slice.
//  - QK^T: per-wave partial over its D-slice (mfma_f32_16x16x32_bf16),
//    deterministic cross-wave reduction through LDS S_part.
//  - online softmax: each q-row owned by one half-wave, shfl_xor butterfly.
//  - PV: P staged in LDS (bf16), V B-frags gathered from global.
// Two paths: bf16-preconverted inputs in d_ws (if it fits), else fp32 direct.

#define B_SZ 4
#define SEQ 2048
#define DIM 1024
#define QBLK 16
#define KVBLK 32
#define NWAVES 8
#define WSLICE 128   // DIM / NWAVES

typedef __bf16 bf16x8 __attribute__((ext_vector_type(8)));
typedef unsigned short u16x8 __attribute__((ext_vector_type(8)));
typedef unsigned short u16x4 __attribute__((ext_vector_type(4)));
typedef float f32x4 __attribute__((ext_vector_type(4)));

__device__ __forceinline__ unsigned short f2bf(float f) {
  union { float f; uint32_t u; } c; c.f = f;
  uint32_t u = c.u;
  u += 0x7FFFu + ((u >> 16) & 1u);   // round-to-nearest-even
  return (unsigned short)(u >> 16);
}

__device__ __forceinline__ bf16x8 packbf8(const float* v) {
  u16x8 u;
#pragma unroll
  for (int j = 0; j < 8; ++j) u[j] = f2bf(v[j]);
  return __builtin_bit_cast(bf16x8, u);
}

// elementwise fp32 -> bf16 (vectorized), grid-stride
__global__ void cvt_bf16_kernel(const float* __restrict__ in,
                                unsigned short* __restrict__ out, int n4) {
  int i = blockIdx.x * blockDim.x + threadIdx.x;
  const int stride = gridDim.x * blockDim.x;
  for (; i < n4; i += stride) {
    f32x4 v = ((const f32x4*)in)[i];
    u16x4 o;
#pragma unroll
    for (int j = 0; j < 4; ++j) o[j] = f2bf(v[j]);
    ((u16x4*)out)[i] = o;
  }
}

template <bool BF16IN>
__global__ void attn_kernel(const void* __restrict__ Qp, const void* __restrict__ Kp,
                            const void* __restrict__ Vp, float* __restrict__ Out) {
  const int tid  = threadIdx.x;
  const int lane = tid & 63;
  const int wv   = tid >> 6;        // wave 0..7 -> D slice
  const int g    = lane >> 4;       // lane group 0..3
  const int i16  = lane & 15;

  const int bid   = blockIdx.x;
  const int batch = bid & (B_SZ - 1);
  const int qt    = (SEQ / QBLK - 1) - (bid >> 2);   // heavy (long causal) tiles first
  const int q0    = qt * QBLK;
  const size_t boff = (size_t)batch * SEQ * DIM;
  const int dbase = wv * WSLICE;

  const float*          Qf = (const float*)Qp;
  const float*          Kf = (const float*)Kp;
  const float*          Vf = (const float*)Vp;
  const unsigned short* Qb = (const unsigned short*)Qp;
  const unsigned short* Kb = (const unsigned short*)Kp;
  const unsigned short* Vb = (const unsigned short*)Vp;

  __shared__ float S_part[NWAVES][QBLK][KVBLK];   // 16 KB partial scores
  __shared__ unsigned short P_lds[QBLK][KVBLK];   // 1 KB bf16 probs
  __shared__ float Mrow[QBLK];
  __shared__ float Lrow[QBLK];
  __shared__ float Arow[QBLK];

  if (tid < QBLK) { Mrow[tid] = -1e30f; Lrow[tid] = 0.f; }

  // Q fragments: A[m=l&15][k = kc*32 + g*8 + jj] over this wave's D slice
  bf16x8 qf[4];
  {
    const size_t rowoff = boff + (size_t)(q0 + i16) * DIM + dbase;
#pragma unroll
    for (int kc = 0; kc < 4; ++kc) {
      const int doff = kc * 32 + g * 8;
      if constexpr (BF16IN) {
        qf[kc] = __builtin_bit_cast(bf16x8, *(const u16x8*)(Qb + rowoff + doff));
      } else {
        f32x4 a = *(const f32x4*)(Qf + rowoff + doff);
        f32x4 b = *(const f32x4*)(Qf + rowoff + doff + 4);
        float tmp[8];
#pragma unroll
        for (int j = 0; j < 4; ++j) { tmp[j] = a[j]; tmp[4 + j] = b[j]; }
        qf[kc] = packbf8(tmp);
      }
    }
  }

  const f32x4 zero4 = {0.f, 0.f, 0.f, 0.f};
  f32x4 o_acc[8];
#pragma unroll
  for (int i = 0; i < 8; ++i) o_acc[i] = zero4;

  __syncthreads();   // Mrow/Lrow init visible

  const int ntiles = (q0 + QBLK + KVBLK - 1) / KVBLK;
  for (int t = 0; t < ntiles; ++t) {
    const int kv0 = t * KVBLK;

    // ---- QK^T partial over this wave's D slice ----
    f32x4 s_acc[2];
    s_acc[0] = zero4; s_acc[1] = zero4;
#pragma unroll
    for (int nt2 = 0; nt2 < 2; ++nt2) {
      const size_t krow = boff + (size_t)(kv0 + nt2 * 16 + i16) * DIM + dbase;
#pragma unroll
      for (int kc = 0; kc < 4; ++kc) {
        const int doff = kc * 32 + g * 8;
        bf16x8 kf;
        if constexpr (BF16IN) {
          kf = __builtin_bit_cast(bf16x8, *(const u16x8*)(Kb + krow + doff));
        } else {
          f32x4 a = *(const f32x4*)(Kf + krow + doff);
          f32x4 b = *(const f32x4*)(Kf + krow + doff + 4);
          float tmp[8];
#pragma unroll
          for (int j = 0; j < 4; ++j) { tmp[j] = a[j]; tmp[4 + j] = b[j]; }
          kf = packbf8(tmp);
        }
        s_acc[nt2] = __builtin_amdgcn_mfma_f32_16x16x32_bf16(qf[kc], kf, s_acc[nt2], 0, 0, 0);
      }
    }
    // C layout: row = g*4 + j, col = i16 (+ nt2*16)
#pragma unroll
    for (int nt2 = 0; nt2 < 2; ++nt2)
#pragma unroll
      for (int j = 0; j < 4; ++j)
        S_part[wv][g * 4 + j][nt2 * 16 + i16] = s_acc[nt2][j];

    __syncthreads();

    // ---- reduce + online softmax: row r owned by half-wave (32 lanes) ----
    {
      const int r = tid >> 5;
      const int c = tid & 31;
      float s = 0.f;
#pragma unroll
      for (int w2 = 0; w2 < NWAVES; ++w2) s += S_part[w2][r][c];
      s *= 0.03125f;   // 1/sqrt(1024); mask-before-scale equivalent below
      const bool valid = (kv0 + c) <= (q0 + r);
      if (!valid) s = -1e30f;
      float tm = s;
#pragma unroll
      for (int off = 1; off < 32; off <<= 1) tm = fmaxf(tm, __shfl_xor(tm, off));
      const float m_old = Mrow[r];
      const float m_new = fmaxf(m_old, tm);
      const float alpha = __expf(m_old - m_new);
      const float p = valid ? __expf(s - m_new) : 0.f;
      float lt = p;
#pragma unroll
      for (int off = 1; off < 32; off <<= 1) lt += __shfl_xor(lt, off);
      if (c == 0) {
        Lrow[r] = alpha * Lrow[r] + lt;
        Mrow[r] = m_new;
        Arow[r] = alpha;
      }
      P_lds[r][c] = f2bf(p);
    }
    __syncthreads();

    // ---- rescale O, then O += P·V over this wave's D slice ----
    float al[4];
#pragma unroll
    for (int j = 0; j < 4; ++j) al[j] = Arow[g * 4 + j];
#pragma unroll
    for (int nt = 0; nt < 8; ++nt)
#pragma unroll
      for (int j = 0; j < 4; ++j) o_acc[nt][j] *= al[j];

    // A frag: P[m=i16][k = g*8 + jj]  (one b128, reused over 8 n-tiles)
    bf16x8 pf = __builtin_bit_cast(bf16x8, *(const u16x8*)(&P_lds[i16][g * 8]));

#pragma unroll
    for (int nt = 0; nt < 8; ++nt) {
      const int dcol = dbase + nt * 16 + i16;
      bf16x8 vfr;
      if constexpr (BF16IN) {
        const unsigned short* vp = Vb + boff + (size_t)(kv0 + g * 8) * DIM + dcol;
        u16x8 uu;
#pragma unroll
        for (int jj = 0; jj < 8; ++jj) uu[jj] = vp[(size_t)jj * DIM];
        vfr = __builtin_bit_cast(bf16x8, uu);
      } else {
        const float* vp = Vf + boff + (size_t)(kv0 + g * 8) * DIM + dcol;
        float tmp[8];
#pragma unroll
        for (int jj = 0; jj < 8; ++jj) tmp[jj] = vp[(size_t)jj * DIM];
        vfr = packbf8(tmp);
      }
      o_acc[nt] = __builtin_amdgcn_mfma_f32_16x16x32_bf16(pf, vfr, o_acc[nt], 0, 0, 0);
    }
  }

  // ---- epilogue: O / l ----
  float linv[4];
#pragma unroll
  for (int j = 0; j < 4; ++j) linv[j] = 1.f / Lrow[g * 4 + j];
#pragma unroll
  for (int nt = 0; nt < 8; ++nt)
#pragma unroll
    for (int j = 0; j < 4; ++j)
      Out[boff + (size_t)(q0 + g * 4 + j) * DIM + dbase + nt * 16 + i16] =
          o_acc[nt][j] * linv[j];
}

extern "C" void kernel_launch(void* const* d_in, const int* in_sizes, int n_in,
                              void* d_out, int out_size, void* d_ws, size_t ws_size,
                              hipStream_t stream) {
  (void)in_sizes; (void)n_in; (void)out_size;
  const float* Q = (const float*)d_in[0];
  const float* K = (const float*)d_in[1];
  const float* V = (const float*)d_in[2];
  float* Out = (float*)d_out;

  const size_t nelem = (size_t)B_SZ * SEQ * DIM;            // 8.4M per tensor
  const size_t bf_bytes = nelem * sizeof(unsigned short);   // 16 MB

  dim3 grid((SEQ / QBLK) * B_SZ);   // 512 blocks, heavy-first inside kernel
  dim3 block(NWAVES * 64);          // 512 threads

  if (ws_size >= 3 * bf_bytes) {
    unsigned short* Qb = (unsigned short*)d_ws;
    unsigned short* Kb = Qb + nelem;
    unsigned short* Vb = Kb + nelem;
    const int n4 = (int)(nelem / 4);
    hipLaunchKernelGGL(cvt_bf16_kernel, dim3(2048), dim3(256), 0, stream, Q, Qb, n4);
    hipLaunchKernelGGL(cvt_bf16_kernel, dim3(2048), dim3(256), 0, stream, K, Kb, n4);
    hipLaunchKernelGGL(cvt_bf16_kernel, dim3(2048), dim3(256), 0, stream, V, Vb, n4);
    hipLaunchKernelGGL((attn_kernel<true>), grid, block, 0, stream,
                       (const void*)Qb, (const void*)Kb, (const void*)Vb, Out);
  } else {
    hipLaunchKernelGGL((attn_kernel<false>), grid, block, 0, stream,
                       (const void*)Q, (const void*)K, (const void*)V, Out);
  }
}

// Round 2
// 274.185 us; speedup vs baseline: 1.1729x; 1.1729x over previous
//
#include <hip/hip_runtime.h>
#include <stdint.h>

// Causal attention, B=4, SQ=SK=2048, D=1024, fp32 in/out, bf16 MFMA compute.
// R2: 16 waves x 64-wide D slice, KVBLK=64, V pre-transposed to [B][D][SK] bf16,
//     K pre-converted to bf16, register prefetch of K(t+1)/V(t), softmax state
//     in registers, 2 barriers per KV tile.

#define B_SZ 4
#define SEQ 2048
#define DIM 1024
#define QBLK 16
#define KVBLK 64
#define NWAVES 16
#define WSLICE 64          // DIM / NWAVES
#define SPAD 68            // padded S_part row (f32 elems): 4*68 % 32 == 16 -> 2-way max

typedef __bf16 bf16x8 __attribute__((ext_vector_type(8)));
typedef unsigned short u16x8 __attribute__((ext_vector_type(8)));
typedef unsigned short u16x4 __attribute__((ext_vector_type(4)));
typedef float f32x4 __attribute__((ext_vector_type(4)));

__device__ __forceinline__ unsigned short f2bf(float f) {
  union { float f; uint32_t u; } c; c.f = f;
  uint32_t u = c.u;
  u += 0x7FFFu + ((u >> 16) & 1u);   // RNE
  return (unsigned short)(u >> 16);
}

__device__ __forceinline__ bf16x8 packbf8(const float* v) {
  u16x8 u;
#pragma unroll
  for (int j = 0; j < 8; ++j) u[j] = f2bf(v[j]);
  return __builtin_bit_cast(bf16x8, u);
}

// fp32 -> bf16 elementwise (for K)
__global__ void cvt_bf16_kernel(const float* __restrict__ in,
                                unsigned short* __restrict__ out, int n4) {
  int i = blockIdx.x * blockDim.x + threadIdx.x;
  const int stride = gridDim.x * blockDim.x;
  for (; i < n4; i += stride) {
    f32x4 v = ((const f32x4*)in)[i];
    u16x4 o;
#pragma unroll
    for (int j = 0; j < 4; ++j) o[j] = f2bf(v[j]);
    ((u16x4*)out)[i] = o;
  }
}

// V[b][sk][d] fp32 -> Vt[b][d][sk] bf16, 32x32 tiles via LDS
__global__ void transpose_v_kernel(const float* __restrict__ in,
                                   unsigned short* __restrict__ out) {
  __shared__ unsigned short tile[32][33];
  const int b  = blockIdx.z;
  const int s0 = blockIdx.y * 32;
  const int d0 = blockIdx.x * 32;
  const int t  = threadIdx.x;          // 256
  const int r  = t >> 3;               // 0..31
  const int c4 = (t & 7) * 4;          // 0,4,...,28
  const size_t ibase = (size_t)b * SEQ * DIM;
  const size_t obase = (size_t)b * DIM * SEQ;

  f32x4 v = *(const f32x4*)(in + ibase + (size_t)(s0 + r) * DIM + d0 + c4);
#pragma unroll
  for (int j = 0; j < 4; ++j) tile[r][c4 + j] = f2bf(v[j]);
  __syncthreads();
  u16x4 o;
#pragma unroll
  for (int j = 0; j < 4; ++j) o[j] = tile[c4 + j][r];
  *(u16x4*)(out + obase + (size_t)(d0 + r) * SEQ + s0 + c4) = o;
}

template <bool BF16IN>
__global__ __launch_bounds__(1024) void attn_kernel(
    const float* __restrict__ Qf, const void* __restrict__ Kp,
    const void* __restrict__ Vp, float* __restrict__ Out) {
  const int tid  = threadIdx.x;
  const int lane = tid & 63;
  const int wv   = tid >> 6;        // 0..15 -> D slice AND softmax row owner
  const int g    = lane >> 4;       // 0..3
  const int i16  = lane & 15;

  const int bid   = blockIdx.x;
  const int batch = bid & (B_SZ - 1);
  const int qt    = (SEQ / QBLK - 1) - (bid >> 2);   // heavy tiles first
  const int q0    = qt * QBLK;
  const size_t boff = (size_t)batch * SEQ * DIM;     // also B*D*SK stride for Vt
  const int dbase = wv * WSLICE;

  const float*          Kf = (const float*)Kp;
  const float*          Vf = (const float*)Vp;   // fallback: V[b][sk][d] fp32
  const unsigned short* Kb = (const unsigned short*)Kp;
  const unsigned short* Vt = (const unsigned short*)Vp;  // Vt[b][d][sk] bf16

  __shared__ float S_part[NWAVES][QBLK][SPAD];   // ~70 KB
  __shared__ unsigned short P_lds[QBLK][KVBLK];  // 2 KB
  __shared__ float Arow[QBLK];
  __shared__ float Lrow[QBLK];

  // ---- prologue: Q fragments (fp32 read, packed once) ----
  bf16x8 qf[2];
  {
    const size_t rowoff = boff + (size_t)(q0 + i16) * DIM + dbase;
#pragma unroll
    for (int kc = 0; kc < 2; ++kc) {
      const int doff = kc * 32 + g * 8;
      f32x4 a = *(const f32x4*)(Qf + rowoff + doff);
      f32x4 b = *(const f32x4*)(Qf + rowoff + doff + 4);
      float tmp[8];
#pragma unroll
      for (int j = 0; j < 4; ++j) { tmp[j] = a[j]; tmp[4 + j] = b[j]; }
      qf[kc] = packbf8(tmp);
    }
  }

  const f32x4 zero4 = {0.f, 0.f, 0.f, 0.f};
  f32x4 o_acc[4];
#pragma unroll
  for (int i = 0; i < 4; ++i) o_acc[i] = zero4;

  float m_reg = -1e30f;   // running max of row q0+wv (uniform across wave)
  float l_reg = 0.f;      // running denom

  const int ntiles = (q0 + QBLK + KVBLK - 1) / KVBLK;

  // ---- K fragments for tile 0 ----
  bf16x8 kreg[4][2];
  {
    const int kv0 = 0;
#pragma unroll
    for (int nt2 = 0; nt2 < 4; ++nt2) {
      const size_t krow = boff + (size_t)(kv0 + nt2 * 16 + i16) * DIM + dbase;
#pragma unroll
      for (int kc = 0; kc < 2; ++kc) {
        const int doff = kc * 32 + g * 8;
        if constexpr (BF16IN) {
          kreg[nt2][kc] = __builtin_bit_cast(bf16x8, *(const u16x8*)(Kb + krow + doff));
        } else {
          f32x4 a = *(const f32x4*)(Kf + krow + doff);
          f32x4 b = *(const f32x4*)(Kf + krow + doff + 4);
          float tmp[8];
#pragma unroll
          for (int j = 0; j < 4; ++j) { tmp[j] = a[j]; tmp[4 + j] = b[j]; }
          kreg[nt2][kc] = packbf8(tmp);
        }
      }
    }
  }

  for (int t = 0; t < ntiles; ++t) {
    const int kv0 = t * KVBLK;

    // ---- V fragments for THIS tile (independent of softmax; issue early) ----
    bf16x8 vreg[2][4];
#pragma unroll
    for (int kc2 = 0; kc2 < 2; ++kc2)
#pragma unroll
      for (int ntd = 0; ntd < 4; ++ntd) {
        if constexpr (BF16IN) {
          // Vt[b][d][sk]: contiguous in kv
          const unsigned short* vp =
              Vt + boff + (size_t)(dbase + ntd * 16 + i16) * SEQ + kv0 + kc2 * 32 + g * 8;
          vreg[kc2][ntd] = __builtin_bit_cast(bf16x8, *(const u16x8*)vp);
        } else {
          const float* vp =
              Vf + boff + (size_t)(kv0 + kc2 * 32 + g * 8) * DIM + dbase + ntd * 16 + i16;
          float tmp[8];
#pragma unroll
          for (int jj = 0; jj < 8; ++jj) tmp[jj] = vp[(size_t)jj * DIM];
          vreg[kc2][ntd] = packbf8(tmp);
        }
      }

    // ---- QK^T partial over this wave's 64-wide D slice ----
    f32x4 s_acc[4];
#pragma unroll
    for (int nt2 = 0; nt2 < 4; ++nt2) {
      s_acc[nt2] = zero4;
#pragma unroll
      for (int kc = 0; kc < 2; ++kc)
        s_acc[nt2] = __builtin_amdgcn_mfma_f32_16x16x32_bf16(qf[kc], kreg[nt2][kc],
                                                             s_acc[nt2], 0, 0, 0);
    }
    // C layout: row(q) = g*4+j, col(kv) = nt2*16 + i16
#pragma unroll
    for (int nt2 = 0; nt2 < 4; ++nt2)
#pragma unroll
      for (int j = 0; j < 4; ++j)
        S_part[wv][g * 4 + j][nt2 * 16 + i16] = s_acc[nt2][j];

    __syncthreads();

    // ---- reduce + online softmax: wave wv owns q-row q0+wv, lane = col ----
    {
      const int c = lane;
      float s = 0.f;
#pragma unroll
      for (int w2 = 0; w2 < NWAVES; ++w2) s += S_part[w2][wv][c];
      s *= 0.03125f;   // 1/sqrt(1024)
      const bool valid = (kv0 + c) <= (q0 + wv);
      if (!valid) s = -1e30f;
      float tm = s;
#pragma unroll
      for (int off = 1; off < 64; off <<= 1) tm = fmaxf(tm, __shfl_xor(tm, off));
      const float m_new = fmaxf(m_reg, tm);
      const float alpha = __expf(m_reg - m_new);
      const float p = valid ? __expf(s - m_new) : 0.f;
      float lt = p;
#pragma unroll
      for (int off = 1; off < 64; off <<= 1) lt += __shfl_xor(lt, off);
      l_reg = alpha * l_reg + lt;
      m_reg = m_new;
      if (lane == 0) Arow[wv] = alpha;
      P_lds[wv][c] = f2bf(p);
    }
    __syncthreads();

    // ---- prefetch K fragments for tile t+1 (hidden under PV) ----
    if (t + 1 < ntiles) {
      const int kvn = kv0 + KVBLK;
#pragma unroll
      for (int nt2 = 0; nt2 < 4; ++nt2) {
        const size_t krow = boff + (size_t)(kvn + nt2 * 16 + i16) * DIM + dbase;
#pragma unroll
        for (int kc = 0; kc < 2; ++kc) {
          const int doff = kc * 32 + g * 8;
          if constexpr (BF16IN) {
            kreg[nt2][kc] = __builtin_bit_cast(bf16x8, *(const u16x8*)(Kb + krow + doff));
          } else {
            f32x4 a = *(const f32x4*)(Kf + krow + doff);
            f32x4 b = *(const f32x4*)(Kf + krow + doff + 4);
            float tmp[8];
#pragma unroll
            for (int j = 0; j < 4; ++j) { tmp[j] = a[j]; tmp[4 + j] = b[j]; }
            kreg[nt2][kc] = packbf8(tmp);
          }
        }
      }
    }

    // ---- rescale O then O += P·V ----
    float al[4];
#pragma unroll
    for (int j = 0; j < 4; ++j) al[j] = Arow[g * 4 + j];
#pragma unroll
    for (int ntd = 0; ntd < 4; ++ntd)
#pragma unroll
      for (int j = 0; j < 4; ++j) o_acc[ntd][j] *= al[j];

#pragma unroll
    for (int kc2 = 0; kc2 < 2; ++kc2) {
      // A frag: P[m=i16][k = kc2*32 + g*8 + jj] (broadcast read)
      bf16x8 pf = __builtin_bit_cast(bf16x8, *(const u16x8*)(&P_lds[i16][kc2 * 32 + g * 8]));
#pragma unroll
      for (int ntd = 0; ntd < 4; ++ntd)
        o_acc[ntd] = __builtin_amdgcn_mfma_f32_16x16x32_bf16(pf, vreg[kc2][ntd],
                                                             o_acc[ntd], 0, 0, 0);
    }
  }

  // ---- epilogue: O / l ----
  if (lane == 0) Lrow[wv] = l_reg;
  __syncthreads();
  float linv[4];
#pragma unroll
  for (int j = 0; j < 4; ++j) linv[j] = 1.f / Lrow[g * 4 + j];
#pragma unroll
  for (int ntd = 0; ntd < 4; ++ntd)
#pragma unroll
    for (int j = 0; j < 4; ++j)
      Out[boff + (size_t)(q0 + g * 4 + j) * DIM + dbase + ntd * 16 + i16] =
          o_acc[ntd][j] * linv[j];
}

extern "C" void kernel_launch(void* const* d_in, const int* in_sizes, int n_in,
                              void* d_out, int out_size, void* d_ws, size_t ws_size,
                              hipStream_t stream) {
  (void)in_sizes; (void)n_in; (void)out_size;
  const float* Q = (const float*)d_in[0];
  const float* K = (const float*)d_in[1];
  const float* V = (const float*)d_in[2];
  float* Out = (float*)d_out;

  const size_t nelem = (size_t)B_SZ * SEQ * DIM;            // 8.4M / tensor
  const size_t bf_bytes = nelem * sizeof(unsigned short);   // 16 MB

  dim3 grid((SEQ / QBLK) * B_SZ);   // 512 blocks
  dim3 block(NWAVES * 64);          // 1024 threads

  if (ws_size >= 2 * bf_bytes) {
    unsigned short* Kb = (unsigned short*)d_ws;
    unsigned short* Vt = Kb + nelem;
    hipLaunchKernelGGL(cvt_bf16_kernel, dim3(2048), dim3(256), 0, stream,
                       K, Kb, (int)(nelem / 4));
    hipLaunchKernelGGL(transpose_v_kernel, dim3(DIM / 32, SEQ / 32, B_SZ), dim3(256),
                       0, stream, V, Vt);
    hipLaunchKernelGGL((attn_kernel<true>), grid, block, 0, stream,
                       Q, (const void*)Kb, (const void*)Vt, Out);
  } else {
    hipLaunchKernelGGL((attn_kernel<false>), grid, block, 0, stream,
                       Q, (const void*)K, (const void*)V, Out);
  }
}

// Round 3
// 266.951 us; speedup vs baseline: 1.2047x; 1.0271x over previous
//
#include <hip/hip_runtime.h>
#include <stdint.h>

// Causal attention, B=4, SQ=SK=2048, D=1024, fp32 in/out, bf16 MFMA compute.
// R3: full-D QK^T per wave (no cross-wave partial reduce). QBLK=32, KVBLK=256,
//     16 waves. Waves parallel over KV cols for QK^T, over D slices for PV.
//     Q staged in LDS (bf16, XOR-swizzled). S/P double-buffered, P aliased
//     in-place over S. K bf16 + V transposed bf16 prepass in d_ws.

#define B_SZ 4
#define SEQ 2048
#define DIM 1024
#define QBLK 32
#define KVBLK 256
#define NWAVES 16
#define SROW 264          // f32 stride for S rows (264 % 32 == 8 -> optimal spans)
#define QROWU16 1024      // Q LDS row stride (u16 elems)

typedef __bf16 bf16x8 __attribute__((ext_vector_type(8)));
typedef unsigned short u16x8 __attribute__((ext_vector_type(8)));
typedef unsigned short u16x4 __attribute__((ext_vector_type(4)));
typedef float f32x4 __attribute__((ext_vector_type(4)));

__device__ __forceinline__ unsigned short f2bf(float f) {
  union { float f; uint32_t u; } c; c.f = f;
  uint32_t u = c.u;
  u += 0x7FFFu + ((u >> 16) & 1u);   // RNE
  return (unsigned short)(u >> 16);
}

__device__ __forceinline__ bf16x8 packbf8(const float* v) {
  u16x8 u;
#pragma unroll
  for (int j = 0; j < 8; ++j) u[j] = f2bf(v[j]);
  return __builtin_bit_cast(bf16x8, u);
}

// fp32 -> bf16 elementwise (for K)
__global__ void cvt_bf16_kernel(const float* __restrict__ in,
                                unsigned short* __restrict__ out, int n4) {
  int i = blockIdx.x * blockDim.x + threadIdx.x;
  const int stride = gridDim.x * blockDim.x;
  for (; i < n4; i += stride) {
    f32x4 v = ((const f32x4*)in)[i];
    u16x4 o;
#pragma unroll
    for (int j = 0; j < 4; ++j) o[j] = f2bf(v[j]);
    ((u16x4*)out)[i] = o;
  }
}

// V[b][sk][d] fp32 -> Vt[b][d][sk] bf16, 32x32 tiles via LDS
__global__ void transpose_v_kernel(const float* __restrict__ in,
                                   unsigned short* __restrict__ out) {
  __shared__ unsigned short tile[32][33];
  const int b  = blockIdx.z;
  const int s0 = blockIdx.y * 32;
  const int d0 = blockIdx.x * 32;
  const int t  = threadIdx.x;          // 256
  const int r  = t >> 3;               // 0..31
  const int c4 = (t & 7) * 4;          // 0,4,...,28
  const size_t ibase = (size_t)b * SEQ * DIM;
  const size_t obase = (size_t)b * DIM * SEQ;

  f32x4 v = *(const f32x4*)(in + ibase + (size_t)(s0 + r) * DIM + d0 + c4);
#pragma unroll
  for (int j = 0; j < 4; ++j) tile[r][c4 + j] = f2bf(v[j]);
  __syncthreads();
  u16x4 o;
#pragma unroll
  for (int j = 0; j < 4; ++j) o[j] = tile[c4 + j][r];
  *(u16x4*)(out + obase + (size_t)(d0 + r) * SEQ + s0 + c4) = o;
}

template <bool BF16IN>
__global__ __launch_bounds__(1024, 4) void attn_kernel(
    const float* __restrict__ Qf, const void* __restrict__ Kp,
    const void* __restrict__ Vp, float* __restrict__ Out) {
  const int tid  = threadIdx.x;
  const int lane = tid & 63;
  const int wv   = tid >> 6;        // 0..15
  const int g    = lane >> 4;       // 0..3
  const int i16  = lane & 15;

  // block -> (batch, qtile): batch groups land on adjacent XCDs; heavy q first
  const int bid   = blockIdx.x;                    // 0..255
  const int batch = (bid >> 1) & 3;
  const int qidx  = (bid >> 3) * 2 + (bid & 1);    // 0..63
  const int qt    = (SEQ / QBLK - 1) - qidx;
  const int q0    = qt * QBLK;
  const int qend  = q0 + QBLK - 1;
  const size_t boff = (size_t)batch * SEQ * DIM;   // also Vt batch stride

  const float*          Kf = (const float*)Kp;
  const float*          Vf = (const float*)Vp;
  const unsigned short* Kb = (const unsigned short*)Kp;
  const unsigned short* Vt = (const unsigned short*)Vp;  // [B][D][SK] bf16

  __shared__ __align__(16) unsigned short Qs[QBLK * QROWU16];  // 64 KB, swizzled
  __shared__ __align__(16) float Sb[2][QBLK][SROW];            // 66 KB, P aliased
  __shared__ float Arow[QBLK];
  __shared__ float Lrow[QBLK];

  // ---- stage Q block: fp32 global -> bf16 LDS, 16B-slot XOR swizzle ----
  {
    const int row = tid >> 5;          // 0..31
    const int s0  = tid & 31;
    const float* qrow = Qf + boff + (size_t)(q0 + row) * DIM;
#pragma unroll
    for (int k = 0; k < 4; ++k) {
      const int slot = s0 + 32 * k;    // 16B slot = 8 bf16 = 8 source f32
      f32x4 a = *(const f32x4*)(qrow + slot * 8);
      f32x4 b = *(const f32x4*)(qrow + slot * 8 + 4);
      float tmp[8];
#pragma unroll
      for (int j = 0; j < 4; ++j) { tmp[j] = a[j]; tmp[4 + j] = b[j]; }
      u16x8 pk;
#pragma unroll
      for (int j = 0; j < 8; ++j) pk[j] = f2bf(tmp[j]);
      const int dslot = slot ^ (row & 7);
      *(u16x8*)(Qs + row * QROWU16 + dslot * 8) = pk;
    }
  }

  const f32x4 zero4 = {0.f, 0.f, 0.f, 0.f};
  f32x4 o_acc[2][4];
#pragma unroll
  for (int mt = 0; mt < 2; ++mt)
#pragma unroll
    for (int n = 0; n < 4; ++n) o_acc[mt][n] = zero4;

  float m_reg[2] = {-1e30f, -1e30f};   // softmax rows wv*2, wv*2+1
  float l_reg[2] = {0.f, 0.f};

  __syncthreads();

  const int ntiles = (q0 + QBLK + KVBLK - 1) / KVBLK;
  const int dbase  = wv * 64;          // PV D slice

  for (int t = 0; t < ntiles; ++t) {
    const int kv0 = t * KVBLK;
    const int buf = t & 1;

    // ---- QK^T: wave owns 16 kv cols, both 16-row m-tiles, full D chain ----
    const int colbase = kv0 + wv * 16;
    if (colbase <= qend) {
      f32x4 sa0 = zero4, sa1 = zero4;
      const int r0 = i16, r1 = 16 + i16;
      const unsigned short* kb = Kb + boff + (size_t)(colbase + i16) * DIM + g * 8;
      const float*          kf32 = Kf + boff + (size_t)(colbase + i16) * DIM + g * 8;
#pragma unroll 2
      for (int ch = 0; ch < 32; ++ch) {
        bf16x8 kf;
        if constexpr (BF16IN) {
          kf = __builtin_bit_cast(bf16x8, *(const u16x8*)(kb + ch * 32));
        } else {
          f32x4 a = *(const f32x4*)(kf32 + ch * 32);
          f32x4 b = *(const f32x4*)(kf32 + ch * 32 + 4);
          float tmp[8];
#pragma unroll
          for (int j = 0; j < 4; ++j) { tmp[j] = a[j]; tmp[4 + j] = b[j]; }
          kf = packbf8(tmp);
        }
        bf16x8 qf0 = __builtin_bit_cast(bf16x8,
            *(const u16x8*)(Qs + r0 * QROWU16 + (((ch * 4 + g) ^ (r0 & 7)) * 8)));
        bf16x8 qf1 = __builtin_bit_cast(bf16x8,
            *(const u16x8*)(Qs + r1 * QROWU16 + (((ch * 4 + g) ^ (r1 & 7)) * 8)));
        sa0 = __builtin_amdgcn_mfma_f32_16x16x32_bf16(qf0, kf, sa0, 0, 0, 0);
        sa1 = __builtin_amdgcn_mfma_f32_16x16x32_bf16(qf1, kf, sa1, 0, 0, 0);
      }
#pragma unroll
      for (int j = 0; j < 4; ++j) {
        Sb[buf][g * 4 + j][wv * 16 + i16]      = sa0[j];
        Sb[buf][16 + g * 4 + j][wv * 16 + i16] = sa1[j];
      }
    }
    __syncthreads();

    // ---- online softmax: wave wv owns rows wv*2, wv*2+1; lane = 4 cols ----
#pragma unroll
    for (int r2 = 0; r2 < 2; ++r2) {
      const int r    = wv * 2 + r2;
      const int grow = q0 + r;
      f32x4 sv = *(const f32x4*)(&Sb[buf][r][lane * 4]);
      float s[4];
#pragma unroll
      for (int j = 0; j < 4; ++j) {
        const bool valid = (kv0 + lane * 4 + j) <= grow;
        s[j] = valid ? sv[j] * 0.03125f : -1e30f;   // 1/sqrt(1024)
      }
      float tm = fmaxf(fmaxf(s[0], s[1]), fmaxf(s[2], s[3]));
#pragma unroll
      for (int off = 1; off < 64; off <<= 1) tm = fmaxf(tm, __shfl_xor(tm, off));
      const float m_new = fmaxf(m_reg[r2], tm);
      const float alpha = __expf(m_reg[r2] - m_new);
      float p[4];
      float lsum = 0.f;
#pragma unroll
      for (int j = 0; j < 4; ++j) { p[j] = __expf(s[j] - m_new); lsum += p[j]; }
#pragma unroll
      for (int off = 1; off < 64; off <<= 1) lsum += __shfl_xor(lsum, off);
      l_reg[r2] = alpha * l_reg[r2] + lsum;
      m_reg[r2] = m_new;
      if (lane == 0) Arow[r] = alpha;
      u16x4 pw;
#pragma unroll
      for (int j = 0; j < 4; ++j) pw[j] = f2bf(p[j]);
      // in-place alias: bf16 P over consumed f32 S (row owned by this wave)
      *(u16x4*)((unsigned short*)(&Sb[buf][r][0]) + lane * 4) = pw;
    }
    __syncthreads();

    // ---- PV: wave owns D slice [dbase, dbase+64); rescale then accumulate ----
    float al[2][4];
#pragma unroll
    for (int mt = 0; mt < 2; ++mt)
#pragma unroll
      for (int j = 0; j < 4; ++j) al[mt][j] = Arow[mt * 16 + g * 4 + j];
#pragma unroll
    for (int mt = 0; mt < 2; ++mt)
#pragma unroll
      for (int n = 0; n < 4; ++n)
#pragma unroll
        for (int j = 0; j < 4; ++j) o_acc[mt][n][j] *= al[mt][j];

    const unsigned short* prow0 = (const unsigned short*)(&Sb[buf][i16][0]);
    const unsigned short* prow1 = (const unsigned short*)(&Sb[buf][16 + i16][0]);
#pragma unroll 2
    for (int kc = 0; kc < 8; ++kc) {
      if (kv0 + kc * 32 <= qend) {
        bf16x8 pf0 = __builtin_bit_cast(bf16x8, *(const u16x8*)(prow0 + kc * 32 + g * 8));
        bf16x8 pf1 = __builtin_bit_cast(bf16x8, *(const u16x8*)(prow1 + kc * 32 + g * 8));
        bf16x8 vf[4];
#pragma unroll
        for (int n = 0; n < 4; ++n) {
          if constexpr (BF16IN) {
            const unsigned short* vp =
                Vt + boff + (size_t)(dbase + n * 16 + i16) * SEQ + kv0 + kc * 32 + g * 8;
            vf[n] = __builtin_bit_cast(bf16x8, *(const u16x8*)vp);
          } else {
            const float* vp =
                Vf + boff + (size_t)(kv0 + kc * 32 + g * 8) * DIM + dbase + n * 16 + i16;
            float tmp[8];
#pragma unroll
            for (int jj = 0; jj < 8; ++jj) tmp[jj] = vp[(size_t)jj * DIM];
            vf[n] = packbf8(tmp);
          }
        }
#pragma unroll
        for (int n = 0; n < 4; ++n) {
          o_acc[0][n] = __builtin_amdgcn_mfma_f32_16x16x32_bf16(pf0, vf[n], o_acc[0][n], 0, 0, 0);
          o_acc[1][n] = __builtin_amdgcn_mfma_f32_16x16x32_bf16(pf1, vf[n], o_acc[1][n], 0, 0, 0);
        }
      }
    }
  }

  // ---- epilogue: O / l ----
  if (lane == 0) { Lrow[wv * 2] = l_reg[0]; Lrow[wv * 2 + 1] = l_reg[1]; }
  __syncthreads();
  float linv[2][4];
#pragma unroll
  for (int mt = 0; mt < 2; ++mt)
#pragma unroll
    for (int j = 0; j < 4; ++j) linv[mt][j] = 1.f / Lrow[mt * 16 + g * 4 + j];
#pragma unroll
  for (int mt = 0; mt < 2; ++mt)
#pragma unroll
    for (int n = 0; n < 4; ++n)
#pragma unroll
      for (int j = 0; j < 4; ++j)
        Out[boff + (size_t)(q0 + mt * 16 + g * 4 + j) * DIM + dbase + n * 16 + i16] =
            o_acc[mt][n][j] * linv[mt][j];
}

extern "C" void kernel_launch(void* const* d_in, const int* in_sizes, int n_in,
                              void* d_out, int out_size, void* d_ws, size_t ws_size,
                              hipStream_t stream) {
  (void)in_sizes; (void)n_in; (void)out_size;
  const float* Q = (const float*)d_in[0];
  const float* K = (const float*)d_in[1];
  const float* V = (const float*)d_in[2];
  float* Out = (float*)d_out;

  const size_t nelem = (size_t)B_SZ * SEQ * DIM;            // 8.4M / tensor
  const size_t bf_bytes = nelem * sizeof(unsigned short);   // 16 MB

  dim3 grid((SEQ / QBLK) * B_SZ);   // 256 blocks
  dim3 block(NWAVES * 64);          // 1024 threads

  if (ws_size >= 2 * bf_bytes) {
    unsigned short* Kb = (unsigned short*)d_ws;
    unsigned short* Vt = Kb + nelem;
    hipLaunchKernelGGL(cvt_bf16_kernel, dim3(2048), dim3(256), 0, stream,
                       K, Kb, (int)(nelem / 4));
    hipLaunchKernelGGL(transpose_v_kernel, dim3(DIM / 32, SEQ / 32, B_SZ), dim3(256),
                       0, stream, V, Vt);
    hipLaunchKernelGGL((attn_kernel<true>), grid, block, 0, stream,
                       Q, (const void*)Kb, (const void*)Vt, Out);
  } else {
    hipLaunchKernelGGL((attn_kernel<false>), grid, block, 0, stream,
                       Q, (const void*)K, (const void*)V, Out);
  }
}